// Round 10
// baseline (187.310 us; speedup 1.0000x reference)
//
#include <hip/hip_runtime.h>
#include <math.h>

#define HW_ (512 * 512)   // 2^18
#define C_ 64
#define K_ 16
#define B_ 8
#define TOTAL_ (B_ * HW_)

// Transpose conv_w [K][C] -> wt [C][K]; per-channel weights become 16
// contiguous floats at a wave-uniform address (scalarizes to s_load).
__global__ __launch_bounds__(256) void transpose_w_kernel(const float* __restrict__ w,
                                                          float* __restrict__ wt) {
    int i = blockIdx.x * blockDim.x + threadIdx.x;  // 0..1023
    if (i < K_ * C_) {
        int k = i >> 6;
        int c = i & 63;
        wt[c * K_ + k] = w[i];
    }
}

// Per-pixel epilogue: log_softmax form + gumbel-max, same fp expression order
// as the jax reference — byte-identical to the passing R0/R3 kernels,
// including the unif loads issued HERE (R6 proved hoisting them regresses).
__device__ __forceinline__ void epilogue(const float* acc, const float4* up4,
                                         const float* __restrict__ palette,
                                         float& cr, float& cg, float& cb) {
    float m = acc[0];
    #pragma unroll
    for (int k = 1; k < K_; ++k) m = fmaxf(m, acc[k]);
    float s = 0.0f;
    #pragma unroll
    for (int k = 0; k < K_; ++k) s += expf(acc[k] - m);
    float ls = logf(s);

    float best = -INFINITY;
    int bi = 0;
    #pragma unroll
    for (int q = 0; q < 4; ++q) {
        float4 v = up4[q];
        float g0 = -logf(-logf(v.x + 1e-20f) + 1e-20f);
        float g1 = -logf(-logf(v.y + 1e-20f) + 1e-20f);
        float g2 = -logf(-logf(v.z + 1e-20f) + 1e-20f);
        float g3 = -logf(-logf(v.w + 1e-20f) + 1e-20f);
        float t0 = (acc[q * 4 + 0] - m) - ls + g0;
        float t1 = (acc[q * 4 + 1] - m) - ls + g1;
        float t2 = (acc[q * 4 + 2] - m) - ls + g2;
        float t3 = (acc[q * 4 + 3] - m) - ls + g3;
        if (t0 > best) { best = t0; bi = q * 4 + 0; }
        if (t1 > best) { best = t1; bi = q * 4 + 1; }
        if (t2 > best) { best = t2; bi = q * 4 + 2; }
        if (t3 > best) { best = t3; bi = q * 4 + 3; }
    }
    cr = palette[bi * 3 + 0];
    cg = palette[bi * 3 + 1];
    cb = palette[bi * 3 + 2];
}

// R3's pixel body byte-for-byte (rotation-loop depth-2 x pipeline, epilogue-
// internal unif loads, 8 waves/SIMD). ONE change: round mapping. A block's
// 4 rounds are now CONSECUTIVE 256-px windows (p = blk*1024 + r*256 + t), so
// each of its 64 channel-streams reads 4 KB sequentially (DRAM page-friendly)
// instead of 1 KB at four addresses 2 MB apart.
__global__ __launch_bounds__(256, 8) void quantizer_kernel(
    const float* __restrict__ x,        // [B][C][HW]
    const float* __restrict__ wt,       // [C][K]
    const float* __restrict__ bias,     // [K]
    const float* __restrict__ palette,  // [K][3]
    const float* __restrict__ unif,     // [B*HW][K]
    float* __restrict__ out)            // [B][3][HW]
{
    const int base = blockIdx.x * 1024 + threadIdx.x;   // blk's 1024-px window

    #pragma unroll 1
    for (int r = 0; r < 4; ++r) {
        int p = base + r * 256;          // consecutive 256-px windows per round
        int b = p >> 18;
        int hw = p & (HW_ - 1);
        const float* xp = x + (size_t)b * C_ * HW_ + (size_t)hw;

        float acc[K_];
        #pragma unroll
        for (int k = 0; k < K_; ++k) acc[k] = bias[k];

        // prologue: load channels 0..7
        float cur[8], nxt[8];
        #pragma unroll
        for (int i = 0; i < 8; ++i) cur[i] = xp[(size_t)i * HW_];

        // steady state: issue 8 loads for group g+1, then 128 FMAs for group g.
        // Per-(pixel,k) accumulation order is ascending c 0..63 — bitwise
        // identical to the passing R0/R3 chain.
        #pragma unroll 1
        for (int g = 0; g < 8; ++g) {
            int c0 = g * 8;
            if (g < 7) {
                #pragma unroll
                for (int i = 0; i < 8; ++i)
                    nxt[i] = xp[(size_t)(c0 + 8 + i) * HW_];
            }
            const float* wp = wt + c0 * K_;   // wave-uniform -> s_load
            #pragma unroll
            for (int k = 0; k < K_; ++k) {
                float a = acc[k];
                #pragma unroll
                for (int i = 0; i < 8; ++i)
                    a = fmaf(cur[i], wp[i * K_ + k], a);
                acc[k] = a;
            }
            if (g < 7) {
                #pragma unroll
                for (int i = 0; i < 8; ++i) cur[i] = nxt[i];
            }
        }

        const float4* up4 = reinterpret_cast<const float4*>(unif + (size_t)p * K_);
        float cr, cg, cb;
        epilogue(acc, up4, palette, cr, cg, cb);

        size_t obase = (size_t)b * 3 * HW_ + (size_t)hw;
        out[obase]                   = cr;
        out[obase + (size_t)HW_]     = cg;
        out[obase + 2 * (size_t)HW_] = cb;
    }
}

extern "C" void kernel_launch(void* const* d_in, const int* in_sizes, int n_in,
                              void* d_out, int out_size, void* d_ws, size_t ws_size,
                              hipStream_t stream) {
    const float* x       = (const float*)d_in[0];
    const float* conv_w  = (const float*)d_in[1];
    const float* conv_b  = (const float*)d_in[2];
    const float* palette = (const float*)d_in[3];
    const float* unif    = (const float*)d_in[4];
    float* out = (float*)d_out;
    float* wt  = (float*)d_ws;   // K_*C_*4 = 4 KiB scratch

    hipLaunchKernelGGL(transpose_w_kernel, dim3(4), dim3(256), 0, stream, conv_w, wt);

    // 2048 blocks x 256 = 524288 threads; each block owns 1024 consecutive px.
    hipLaunchKernelGGL(quantizer_kernel, dim3(2048), dim3(256), 0, stream,
                       x, wt, conv_b, palette, unif, out);
}